// Round 2
// 578.823 us; speedup vs baseline: 1.1008x; 1.1008x over previous
//
#include <hip/hip_runtime.h>

#define BB 32
#define SS 4096
#define DD 1024
#define HH 256

typedef float vfloat4 __attribute__((ext_vector_type(4)));

// K1: direct DFT, first 16 bins, both channels. 1024 blocks x 64 threads,
// one wave per (b, channel, bin). Pattern is 1 MiB -> L2-resident; each wave
// does 64 strided iterations with hardware sin/cos. ~few us.
__global__ void k_dft(const float* __restrict__ pat, float* __restrict__ freq) {
    int blk = blockIdx.x;            // 0..1023
    int k = blk & 15;
    int c = (blk >> 4) & 1;
    int b = blk >> 5;
    int lane = threadIdx.x;          // 0..63
    const float w = 6.28318530717958647692f / 4096.0f;
    float re = 0.f, im = 0.f;
    for (int t = lane; t < SS; t += 64) {
        float x = pat[(b * SS + t) * 2 + c];
        int m = (k * t) & 4095;      // arg reduction: period 4096
        float ang = w * (float)m;
        re += x * __cosf(ang);
        im += x * __sinf(ang);       // sign irrelevant for magnitude
    }
    for (int off = 32; off > 0; off >>= 1) {
        re += __shfl_down(re, off);
        im += __shfl_down(im, off);
    }
    if (lane == 0) freq[b * 32 + c * 16 + k] = sqrtf(re * re + im * im);
}

// K2 (fused): blocks 0..31 compute fWf[b][h]; blocks 32..287 compute the
// folded coefficients with one WAVE per output row d (coalesced float4 reads
// of Wo row + shfl-tree reduction) instead of 4 blocks of stride-4KB lane
// access. 288 blocks x 256 threads.
__global__ __launch_bounds__(256) void k_fwf_coef(
        const float* __restrict__ freq, const float* __restrict__ Wf,
        const float* __restrict__ bfv, float* __restrict__ fWf,
        const float* __restrict__ Wp, const float* __restrict__ Wv,
        const float* __restrict__ Wa, const float* __restrict__ bp,
        const float* __restrict__ bv, const float* __restrict__ ba,
        const float* __restrict__ Wo, const float* __restrict__ bo,
        float* __restrict__ coef, float* __restrict__ base) {
    if (blockIdx.x < 32) {
        // fWf[b][h] = bf[h] + sum_j freq[b][j] * Wf[h][j]
        int b = blockIdx.x;
        int h = threadIdx.x;
        float acc = bfv[h];
#pragma unroll
        for (int j = 0; j < 32; ++j)
            acc += freq[b * 32 + j] * Wf[h * 32 + j];
        fWf[b * HH + h] = acc;
        return;
    }
    // coef role: wave wid handles output row d = wid. 256 blocks * 4 waves.
    int d = (blockIdx.x - 32) * 4 + (threadIdx.x >> 6);   // 0..1023
    int lane = threadIdx.x & 63;
    int h0 = lane * 4;                                    // 0..252
    const float* wo = Wo + (size_t)d * DD;
    // coalesced: wave reads 1KB contiguous per segment
    float4 w0 = *(const float4*)(wo + h0);
    float4 w1 = *(const float4*)(wo + 256 + h0);
    float4 w2 = *(const float4*)(wo + 512 + h0);
    // Wp/Wv/Wa are [256][2]; 8 consecutive floats cover h0..h0+3
    float4 p0 = *(const float4*)(Wp + h0 * 2);
    float4 p1 = *(const float4*)(Wp + h0 * 2 + 4);
    float4 v0 = *(const float4*)(Wv + h0 * 2);
    float4 v1 = *(const float4*)(Wv + h0 * 2 + 4);
    float4 a0 = *(const float4*)(Wa + h0 * 2);
    float4 a1 = *(const float4*)(Wa + h0 * 2 + 4);
    float4 bpq = *(const float4*)(bp + h0);
    float4 bvq = *(const float4*)(bv + h0);
    float4 baq = *(const float4*)(ba + h0);

    float mp0 = w0.x * p0.x + w0.y * p0.z + w0.z * p1.x + w0.w * p1.z;
    float mp1 = w0.x * p0.y + w0.y * p0.w + w0.z * p1.y + w0.w * p1.w;
    float mv0 = w1.x * v0.x + w1.y * v0.z + w1.z * v1.x + w1.w * v1.z;
    float mv1 = w1.x * v0.y + w1.y * v0.w + w1.z * v1.y + w1.w * v1.w;
    float ma0 = w2.x * a0.x + w2.y * a0.z + w2.z * a1.x + w2.w * a1.z;
    float ma1 = w2.x * a0.y + w2.y * a0.w + w2.z * a1.y + w2.w * a1.w;
    float bs  = w0.x * bpq.x + w0.y * bpq.y + w0.z * bpq.z + w0.w * bpq.w
              + w1.x * bvq.x + w1.y * bvq.y + w1.z * bvq.z + w1.w * bvq.w
              + w2.x * baq.x + w2.y * baq.y + w2.z * baq.z + w2.w * baq.w;

    for (int off = 32; off > 0; off >>= 1) {
        mp0 += __shfl_down(mp0, off);
        mp1 += __shfl_down(mp1, off);
        mv0 += __shfl_down(mv0, off);
        mv1 += __shfl_down(mv1, off);
        ma0 += __shfl_down(ma0, off);
        ma1 += __shfl_down(ma1, off);
        bs  += __shfl_down(bs,  off);
    }
    if (lane == 0) {
        coef[0 * DD + d] = mp0; coef[1 * DD + d] = mp1;
        coef[2 * DD + d] = mv0; coef[3 * DD + d] = mv1;
        coef[4 * DD + d] = ma0; coef[5 * DD + d] = ma1;
        base[d] = bo[d] + bs;
    }
}

// K3: cb[b][d] = base[d] + sum_h Wo[d][768+h] * fWf[b][h].
// One wave per (b,d): coalesced float4 row reads + shfl reduce.
// 8192 blocks x 256 threads = 32768 waves.
__global__ __launch_bounds__(256) void k_cb(
        const float* __restrict__ Wo, const float* __restrict__ fWf,
        const float* __restrict__ base, float* __restrict__ cb) {
    int wid = blockIdx.x * 4 + (threadIdx.x >> 6);  // 0..32767 = b*1024 + d
    int lane = threadIdx.x & 63;
    int b = wid >> 10;
    int d = wid & 1023;
    int h0 = lane * 4;
    float4 w = *(const float4*)(Wo + (size_t)d * DD + 768 + h0);
    float4 f = *(const float4*)(fWf + b * HH + h0);
    float acc = w.x * f.x + w.y * f.y + w.z * f.z + w.w * f.w;
    for (int off = 32; off > 0; off >>= 1) acc += __shfl_down(acc, off);
    if (lane == 0) cb[wid] = base[d] + acc;
}

// K4: streaming epilogue. out[b,s,d] = p.Mp[d] + v.Mv[d] + a.Ma[d] + cb[b,d].
// 2048 blocks x 256 threads, 64 rows/block -> 32 waves/CU. Rolling P/Q/R
// registers (1 uniform load per row) + nontemporal float4 stores (output is
// write-once, never re-read -> skip L2 allocate).
__global__ __launch_bounds__(256) void k_main(
        const float2* __restrict__ pat2, // pattern as float2 per (b,s)
        const float* __restrict__ coef,  // [6][1024]
        const float* __restrict__ cb,    // [32][1024]
        float* __restrict__ out) {
    int t = threadIdx.x;
    int d0 = t * 4;
    const int ROWS = 64;
    const int blkPerB = SS / ROWS;       // 64
    int b = blockIdx.x / blkPerB;
    int s0 = (blockIdx.x % blkPerB) * ROWS;

    float mp0[4], mp1[4], mv0[4], mv1[4], ma0[4], ma1[4], c4[4];
#pragma unroll
    for (int j = 0; j < 4; ++j) {
        mp0[j] = coef[0 * DD + d0 + j];
        mp1[j] = coef[1 * DD + d0 + j];
        mv0[j] = coef[2 * DD + d0 + j];
        mv1[j] = coef[3 * DD + d0 + j];
        ma0[j] = coef[4 * DD + d0 + j];
        ma1[j] = coef[5 * DD + d0 + j];
        c4[j]  = cb[b * DD + d0 + j];
    }
    const float2* prow = pat2 + (size_t)b * SS;
    float2 Q, R;
    if (s0 >= 2) { Q = prow[s0 - 1]; R = prow[s0 - 2]; }
    else         { Q = prow[0];      R = prow[0]; }      // only s0==0 case

    for (int i = 0; i < ROWS; ++i) {
        int s = s0 + i;
        float2 P = prow[s];
        float v0, v1, a0, a1;
        if (s >= 2) {                        // uniform branch per iteration
            v0 = P.x - Q.x; v1 = P.y - Q.y;
            a0 = v0 - (Q.x - R.x); a1 = v1 - (Q.y - R.y);
        } else if (s == 1) {
            v0 = P.x - Q.x; v1 = P.y - Q.y; a0 = v0; a1 = v1;
        } else {
            v0 = 0.f; v1 = 0.f; a0 = 0.f; a1 = 0.f;
        }
        vfloat4 o;
        o.x = c4[0] + P.x * mp0[0] + P.y * mp1[0] + v0 * mv0[0] + v1 * mv1[0] + a0 * ma0[0] + a1 * ma1[0];
        o.y = c4[1] + P.x * mp0[1] + P.y * mp1[1] + v0 * mv0[1] + v1 * mv1[1] + a0 * ma0[1] + a1 * ma1[1];
        o.z = c4[2] + P.x * mp0[2] + P.y * mp1[2] + v0 * mv0[2] + v1 * mv1[2] + a0 * ma0[2] + a1 * ma1[2];
        o.w = c4[3] + P.x * mp0[3] + P.y * mp1[3] + v0 * mv0[3] + v1 * mv1[3] + a0 * ma0[3] + a1 * ma1[3];
        __builtin_nontemporal_store(o, (vfloat4*)(out + (((size_t)(b * SS + s)) << 10) + d0));
        R = Q; Q = P;
    }
}

extern "C" void kernel_launch(void* const* d_in, const int* in_sizes, int n_in,
                              void* d_out, int out_size, void* d_ws, size_t ws_size,
                              hipStream_t stream) {
    const float* pattern = (const float*)d_in[0];
    const float* Wp = (const float*)d_in[1];
    const float* bp = (const float*)d_in[2];
    const float* Wv = (const float*)d_in[3];
    const float* bv = (const float*)d_in[4];
    const float* Wa = (const float*)d_in[5];
    const float* ba = (const float*)d_in[6];
    const float* Wf = (const float*)d_in[7];
    const float* bfv = (const float*)d_in[8];
    const float* Wo = (const float*)d_in[9];
    const float* bo = (const float*)d_in[10];

    float* ws   = (float*)d_ws;
    float* freq = ws;            // 1024 floats
    float* fWf  = ws + 1024;     // 8192 floats
    float* coef = ws + 9216;     // 6144 floats
    float* base = ws + 15360;    // 1024 floats
    float* cb   = ws + 16384;    // 32768 floats   (total 192 KiB)
    float* out  = (float*)d_out;

    k_dft     <<<1024, 64, 0, stream>>>(pattern, freq);
    k_fwf_coef<<<288, 256, 0, stream>>>(freq, Wf, bfv, fWf,
                                        Wp, Wv, Wa, bp, bv, ba, Wo, bo, coef, base);
    k_cb      <<<8192, 256, 0, stream>>>(Wo, fWf, base, cb);
    k_main    <<<2048, 256, 0, stream>>>((const float2*)pattern, coef, cb, out);
}